// Round 1
// baseline (590.730 us; speedup 1.0000x reference)
//
#include <hip/hip_runtime.h>
#include <hip/hip_bf16.h>
#include <math.h>

// Problem constants
#define B_  2
#define C_  256
#define H_  64
#define W_  64
#define HP_ 66
#define WP_ 66
#define N_  9
#define NPIX_ (B_ * H_ * W_)          // 8192
#define XT_BSTRIDE (HP_ * WP_ * C_)   // 1115136 floats per batch
#define THETA_ 0.7f

// ---------------- pad + transpose x -> xT[b][hp][wp][c] (zero padded) --------
__global__ __launch_bounds__(256) void pad_transpose(const float* __restrict__ x,
                                                     float* __restrict__ xT) {
  int blk = blockIdx.x;              // b(2) * h(64) * cg(4) = 512
  int cg = blk & 3;
  int h  = (blk >> 2) & 63;
  int b  = blk >> 8;
  __shared__ float tile[64][65];
  const float* xp = x + ((size_t)(b * 256 + cg * 64)) * 4096 + h * 64;
#pragma unroll
  for (int j = 0; j < 16; j++) {
    int idx = j * 256 + threadIdx.x;
    int ci = idx >> 6, w = idx & 63;
    tile[ci][w] = xp[(size_t)ci * 4096 + w];
  }
  __syncthreads();
  float* xo = xT + (size_t)b * XT_BSTRIDE + ((h + 1) * 66 + 1) * 256 + cg * 64;
#pragma unroll
  for (int j = 0; j < 16; j++) {
    int idx = j * 256 + threadIdx.x;
    int w = idx >> 6, ci = idx & 63;
    xo[(size_t)w * 256 + ci] = tile[ci][w];
  }
}

// ---------------- prepack weights -------------------------------------------
// W1[kp][c][oc27]  (oc<18: p_w, else m_w)           62208 floats
// Wd[(n*256+c)][o] = dconv_w[o][c][n]               589824 floats
// Wc[(t*256+c)][o] = cdc eff. weight (5 taps)       327680 floats
__global__ void prepack(const float* __restrict__ p_w, const float* __restrict__ m_w,
                        const float* __restrict__ dconv_w, const float* __restrict__ cdc_w,
                        float* __restrict__ W1, float* __restrict__ Wd,
                        float* __restrict__ Wc) {
  int i = blockIdx.x * 256 + threadIdx.x;
  if (i < 62208) {
    int oc = i % 27;
    int c  = (i / 27) & 255;
    int kp = i / (27 * 256);
    float v = (oc < 18) ? p_w[((size_t)oc * 256 + c) * 9 + kp]
                        : m_w[((size_t)(oc - 18) * 256 + c) * 9 + kp];
    W1[i] = v;
  }
  int j = i - 62208;
  if (j >= 0 && j < 589824) {
    int o = j & 255;
    int c = (j >> 8) & 255;
    int n = j >> 16;
    Wd[j] = dconv_w[((size_t)o * 256 + c) * 9 + n];
  }
  int j2 = i - 62208 - 589824;
  if (j2 >= 0 && j2 < 327680) {
    int o = j2 & 255;
    int c = (j2 >> 8) & 255;
    int t = j2 >> 16;
    const float* cw = cdc_w + ((size_t)o * 256 + c) * 5;
    float v = cw[t];
    if (t == 2) v -= THETA_ * (cw[0] + cw[1] + cw[2] + cw[3] + cw[4]);
    Wc[j2] = v;
  }
}

// ---------------- offset / modulation conv (27 channels) --------------------
__global__ __launch_bounds__(256) void offmod_conv(const float* __restrict__ xT,
                                                   const float* __restrict__ W1,
                                                   const float* __restrict__ p_b,
                                                   const float* __restrict__ m_b,
                                                   float* __restrict__ offmod) {
  int i = blockIdx.x * 256 + threadIdx.x;
  if (i >= 221184) return;
  int oc = i % 27;
  int p  = i / 27;
  int b  = p >> 12;
  int hw = p & 4095;
  int h  = hw >> 6, w = hw & 63;
  const float* xb = xT + (size_t)b * XT_BSTRIDE;
  float acc = (oc < 18) ? p_b[oc] : m_b[oc - 18];
#pragma unroll
  for (int kp = 0; kp < 9; kp++) {
    const float* xr = xb + ((h + kp / 3) * 66 + (w + kp % 3)) * 256;
    const float* wr = W1 + kp * 256 * 27 + oc;
#pragma unroll 4
    for (int c = 0; c < 256; c++) acc += xr[c] * wr[c * 27];
  }
  offmod[(size_t)(b * 27 + oc) * 4096 + hw] = acc;
}

// ---------------- sampling params: 4 corner indices + 4 (g*m) weights -------
__global__ void sample_params(const float* __restrict__ offmod,
                              int4* __restrict__ sidx, float4* __restrict__ sg) {
  int i = blockIdx.x * 256 + threadIdx.x;
  if (i >= NPIX_ * N_) return;
  int n = i % 9;
  int p = i / 9;
  int b = p >> 12;
  int hw = p & 4095;
  int h = hw >> 6, w = hw & 63;
  const float* om = offmod + (size_t)b * 27 * 4096;
  float offx = om[(size_t)n * 4096 + hw];
  float offy = om[(size_t)(9 + n) * 4096 + hw];
  float mraw = om[(size_t)(18 + n) * 4096 + hw];
  float px = offx + (float)(h + n / 3);   // (n/3 - 1) + (h + 1)
  float py = offy + (float)(w + n % 3);
  float fx = floorf(px), fy = floorf(py);
  float qx0 = fminf(fmaxf(fx, 0.f), 65.f);
  float qy0 = fminf(fmaxf(fy, 0.f), 65.f);
  float qx1 = fminf(fmaxf(fx + 1.f, 0.f), 65.f);
  float qy1 = fminf(fmaxf(fy + 1.f, 0.f), 65.f);
  float pxc = fminf(fmaxf(px, 0.f), 65.f);
  float pyc = fminf(fmaxf(py, 0.f), 65.f);
  float gx0 = 1.f + (qx0 - pxc);
  float gx1 = 1.f - (qx1 - pxc);
  float gy0 = 1.f + (qy0 - pyc);
  float gy1 = 1.f - (qy1 - pyc);
  float m = 1.f / (1.f + expf(-mraw));
  sidx[i] = make_int4((int)qx0 * 66 + (int)qy0, (int)qx1 * 66 + (int)qy1,
                      (int)qx0 * 66 + (int)qy1, (int)qx1 * 66 + (int)qy0);
  sg[i] = make_float4(gx0 * gy0 * m, gx1 * gy1 * m, gx0 * gy1 * m, gx1 * gy0 * m);
}

// ---------------- fused gather + GEMM ---------------------------------------
// A[M=8192][K] built on the fly (deform: bilinear gather; cdc: 5-tap neighbor)
// Bmat[K][256], out channels [ochan0 .. ochan0+255], ReLU epilogue.
// BM=128, BN=64, BK=32, 512 threads, 4x4 micro-tile.
template <int KTOT, bool CDC>
__global__ __launch_bounds__(512) void gemm_fused(
    const float* __restrict__ xT, const float* __restrict__ Bmat,
    const int4* __restrict__ sidx, const float4* __restrict__ sg,
    float* __restrict__ out) {
  const int BM = 128, BN = 64, BK = 32;
  __shared__ float Alds[BK][BM + 4];  // kk-major, pad 4
  __shared__ float Blds[BK][BN];
  int tid = threadIdx.x;
  int pbase = blockIdx.x * BM;
  int b = pbase >> 12;
  const float* xb = xT + (size_t)b * XT_BSTRIDE;
  int obase = blockIdx.y * BN;
  float acc[4][4] = {};
  int cc  = tid & 31;
  int mm0 = tid >> 5;   // 0..15
  int ty  = tid >> 4;   // 0..31  (M)
  int tx  = tid & 15;   //        (N)

  for (int kb = 0; kb < KTOT; kb += BK) {
    int c0 = kb & 255;
    if (!CDC) {
      int n = kb >> 8;
      const float* xc = xb + c0 + cc;
#pragma unroll
      for (int r = 0; r < 8; r++) {
        int mm = mm0 + r * 16;
        int s = (pbase + mm) * 9 + n;
        int4 q = sidx[s];
        float4 g = sg[s];
        float v = g.x * xc[(size_t)q.x * 256] + g.y * xc[(size_t)q.y * 256] +
                  g.z * xc[(size_t)q.z * 256] + g.w * xc[(size_t)q.w * 256];
        Alds[cc][mm] = v;
      }
    } else {
      int t = kb >> 8;
      int dh = (t == 0) ? 0 : ((t == 4) ? 2 : 1);
      int dw = (t == 0 || t == 4) ? 1 : (t - 1);
#pragma unroll
      for (int r = 0; r < 8; r++) {
        int mm = mm0 + r * 16;
        int p = pbase + mm;
        int hw = p & 4095;
        int h = hw >> 6, w = hw & 63;
        Alds[cc][mm] = xb[((h + dh) * 66 + (w + dw)) * 256 + c0 + cc];
      }
    }
    {
      int jj = tid & 63;
      int kk0 = tid >> 6;  // 0..7
#pragma unroll
      for (int r = 0; r < 4; r++) {
        int kk = kk0 + r * 8;
        Blds[kk][jj] = Bmat[(size_t)(kb + kk) * 256 + obase + jj];
      }
    }
    __syncthreads();
#pragma unroll
    for (int kk = 0; kk < BK; kk++) {
      float4 av = *(const float4*)&Alds[kk][ty * 4];
      float4 bv = *(const float4*)&Blds[kk][tx * 4];
      float a[4] = {av.x, av.y, av.z, av.w};
      float bb[4] = {bv.x, bv.y, bv.z, bv.w};
#pragma unroll
      for (int i = 0; i < 4; i++)
#pragma unroll
        for (int e = 0; e < 4; e++) acc[i][e] += a[i] * bb[e];
    }
    __syncthreads();
  }
  const int ochan0 = CDC ? 256 : 0;
#pragma unroll
  for (int i = 0; i < 4; i++) {
    int p = pbase + ty * 4 + i;
    int hw = p & 4095;
#pragma unroll
    for (int e = 0; e < 4; e++) {
      int o = ochan0 + obase + tx * 4 + e;
      out[((size_t)(b * 512 + o)) * 4096 + hw] = fmaxf(acc[i][e], 0.f);
    }
  }
}

// ---------------- launch ----------------------------------------------------
extern "C" void kernel_launch(void* const* d_in, const int* in_sizes, int n_in,
                              void* d_out, int out_size, void* d_ws, size_t ws_size,
                              hipStream_t stream) {
  (void)in_sizes; (void)n_in; (void)out_size; (void)ws_size;
  const float* x       = (const float*)d_in[0];
  const float* p_w     = (const float*)d_in[1];
  const float* p_b     = (const float*)d_in[2];
  const float* m_w     = (const float*)d_in[3];
  const float* m_b     = (const float*)d_in[4];
  const float* dconv_w = (const float*)d_in[5];
  const float* cdc_w   = (const float*)d_in[6];
  float* out = (float*)d_out;
  char* ws = (char*)d_ws;

  float* xT     = (float*)(ws);                // 8,921,088 B
  float* offmod = (float*)(ws + 8921088);      //   884,736 B
  float* W1     = (float*)(ws + 9805824);      //   248,832 B
  float* Wd     = (float*)(ws + 10054656);     // 2,359,296 B
  float* Wc     = (float*)(ws + 12413952);     // 1,310,720 B
  int4*  sidx   = (int4*)(ws + 13724672);      // 1,179,648 B
  float4* sg    = (float4*)(ws + 14904320);    // 1,179,648 B

  hipMemsetAsync(xT, 0, 8921088, stream);
  pad_transpose<<<512, 256, 0, stream>>>(x, xT);
  prepack<<<3827, 256, 0, stream>>>(p_w, m_w, dconv_w, cdc_w, W1, Wd, Wc);
  offmod_conv<<<864, 256, 0, stream>>>(xT, W1, p_b, m_b, offmod);
  sample_params<<<288, 256, 0, stream>>>(offmod, sidx, sg);
  gemm_fused<2304, false><<<dim3(64, 4), 512, 0, stream>>>(xT, Wd, sidx, sg, out);
  gemm_fused<1280, true ><<<dim3(64, 4), 512, 0, stream>>>(xT, Wc, sidx, sg, out);
}

// Round 2
// 97.965 us; speedup vs baseline: 6.0300x; 6.0300x over previous
//
#include <hip/hip_runtime.h>
#include <hip/hip_bf16.h>
#include <math.h>

#define XT_BSTRIDE (66*66*256)
#define THETA_ 0.7f

typedef unsigned short u16;
typedef __attribute__((ext_vector_type(8))) short bf16x8;
typedef __attribute__((ext_vector_type(4))) float f32x4;

#define GLOAD16(gp, lp) __builtin_amdgcn_global_load_lds( \
    (const __attribute__((address_space(1))) unsigned int*)(gp), \
    (__attribute__((address_space(3))) unsigned int*)(lp), 16, 0, 0)

__device__ __forceinline__ float bf2f(u16 v) {
  union { unsigned u; float f; } x; x.u = ((unsigned)v) << 16; return x.f;
}
__device__ __forceinline__ u16 f2bf(float f) {
  __hip_bfloat16 h = __float2bfloat16(f);
  return *(u16*)&h;
}

// swizzled element index within a [rows][K] bf16 matrix: per 64-k tile, the
// 8-element chunks are XOR-permuted by (row&7) so that linear global_load_lds
// (8 rows x 8 chunks per wave-instr) lands them at XOR-swizzled LDS slots.
__device__ __forceinline__ size_t swz_idx(int row, int k, int KT) {
  int kt = k >> 6, kc = (k >> 3) & 7, kj = k & 7;
  return (size_t)row * KT + kt * 64 + ((kc ^ (row & 7)) << 3) + kj;
}

// ---------------- pad + transpose + bf16: x -> xTb[b][hp][wp][c] ------------
__global__ __launch_bounds__(256) void pad_transpose(const float* __restrict__ x,
                                                     u16* __restrict__ xTb) {
  int blk = blockIdx.x;              // b(2) * h(64) * cg(4) = 512
  int cg = blk & 3;
  int h  = (blk >> 2) & 63;
  int b  = blk >> 8;
  __shared__ float tile[64][65];
  const float* xp = x + ((size_t)(b * 256 + cg * 64)) * 4096 + h * 64;
#pragma unroll
  for (int j = 0; j < 16; j++) {
    int idx = j * 256 + threadIdx.x;
    int ci = idx >> 6, w = idx & 63;
    tile[ci][w] = xp[(size_t)ci * 4096 + w];
  }
  __syncthreads();
  u16* xo = xTb + (size_t)b * XT_BSTRIDE + ((h + 1) * 66 + 1) * 256 + cg * 64;
#pragma unroll
  for (int j = 0; j < 16; j++) {
    int idx = j * 256 + threadIdx.x;
    int w = idx >> 6, ci = idx & 63;
    xo[(size_t)w * 256 + ci] = f2bf(tile[ci][w]);
  }
}

// ---------------- prepack weights (bf16, B^T, swizzled) ---------------------
// W1t[32][2304]  (o<18: p_w, o<27: m_w, else 0), k = kp*256+c
// Wdt[256][2304] k = n*256+c ;  Wct[256][1280] k = t*256+c (center tap folded)
__global__ void prepack_w(const float* __restrict__ p_w, const float* __restrict__ m_w,
                          const float* __restrict__ dconv_w, const float* __restrict__ cdc_w,
                          u16* __restrict__ W1t, u16* __restrict__ Wdt,
                          u16* __restrict__ Wct) {
  int i = blockIdx.x * 256 + threadIdx.x;
  if (i < 73728) {
    int o = i / 2304, k = i % 2304;
    int kp = k >> 8, c = k & 255;
    float v = 0.f;
    if (o < 18)      v = p_w[((size_t)o * 256 + c) * 9 + kp];
    else if (o < 27) v = m_w[((size_t)(o - 18) * 256 + c) * 9 + kp];
    W1t[swz_idx(o, k, 2304)] = f2bf(v);
    return;
  }
  int j = i - 73728;
  if (j < 589824) {
    int o = j / 2304, k = j % 2304;
    int n = k >> 8, c = k & 255;
    Wdt[swz_idx(o, k, 2304)] = f2bf(dconv_w[((size_t)o * 256 + c) * 9 + n]);
    return;
  }
  int j2 = j - 589824;
  if (j2 < 327680) {
    int o = j2 / 1280, k = j2 % 1280;
    int t = k >> 8, c = k & 255;
    const float* cw = cdc_w + ((size_t)o * 256 + c) * 5;
    float v = cw[t];
    if (t == 2) v -= THETA_ * (cw[0] + cw[1] + cw[2] + cw[3] + cw[4]);
    Wct[swz_idx(o, k, 1280)] = f2bf(v);
  }
}

// ---------------- sampling params: 4 corner indices + 4 (g*m) weights -------
__global__ void sample_params(const float* __restrict__ offmod,
                              int4* __restrict__ sidx, float4* __restrict__ sg) {
  int i = blockIdx.x * 256 + threadIdx.x;
  if (i >= 73728) return;
  int n = i % 9;
  int p = i / 9;
  int b = p >> 12;
  int hw = p & 4095;
  int h = hw >> 6, w = hw & 63;
  const float* om = offmod + (size_t)b * 27 * 4096;
  float offx = om[(size_t)n * 4096 + hw];
  float offy = om[(size_t)(9 + n) * 4096 + hw];
  float mraw = om[(size_t)(18 + n) * 4096 + hw];
  float px = offx + (float)(h + n / 3);
  float py = offy + (float)(w + n % 3);
  float fx = floorf(px), fy = floorf(py);
  float qx0 = fminf(fmaxf(fx, 0.f), 65.f);
  float qy0 = fminf(fmaxf(fy, 0.f), 65.f);
  float qx1 = fminf(fmaxf(fx + 1.f, 0.f), 65.f);
  float qy1 = fminf(fmaxf(fy + 1.f, 0.f), 65.f);
  float pxc = fminf(fmaxf(px, 0.f), 65.f);
  float pyc = fminf(fmaxf(py, 0.f), 65.f);
  float gx0 = 1.f + (qx0 - pxc);
  float gx1 = 1.f - (qx1 - pxc);
  float gy0 = 1.f + (qy0 - pyc);
  float gy1 = 1.f - (qy1 - pyc);
  float m = 1.f / (1.f + expf(-mraw));
  sidx[i] = make_int4((int)qx0 * 66 + (int)qy0, (int)qx1 * 66 + (int)qy1,
                      (int)qx0 * 66 + (int)qy1, (int)qx1 * 66 + (int)qy0);
  sg[i] = make_float4(gx0 * gy0 * m, gx1 * gy1 * m, gx0 * gy1 * m, gx1 * gy0 * m);
}

// ---------------- build A_d (bilinear gather), bf16, pre-swizzled -----------
__global__ __launch_bounds__(256) void gather_Ad(const u16* __restrict__ xTb,
                                                 const int4* __restrict__ sidx,
                                                 const float4* __restrict__ sg,
                                                 u16* __restrict__ Ad) {
  int gid = blockIdx.x * 256 + threadIdx.x;   // 2359296 total
  int q = gid & 31;                            // channel chunk (8 ch)
  int s = gid >> 5;                            // p*9+n
  int p = s / 9, n = s - p * 9;
  int b = p >> 12;
  int4 qi = sidx[s];
  float4 g = sg[s];
  const u16* xb = xTb + (size_t)b * XT_BSTRIDE + q * 8;
  bf16x8 a0 = *(const bf16x8*)(xb + (size_t)qi.x * 256);
  bf16x8 a1 = *(const bf16x8*)(xb + (size_t)qi.y * 256);
  bf16x8 a2 = *(const bf16x8*)(xb + (size_t)qi.z * 256);
  bf16x8 a3 = *(const bf16x8*)(xb + (size_t)qi.w * 256);
  bf16x8 ov;
#pragma unroll
  for (int j = 0; j < 8; j++) {
    float v = g.x * bf2f((u16)a0[j]) + g.y * bf2f((u16)a1[j]) +
              g.z * bf2f((u16)a2[j]) + g.w * bf2f((u16)a3[j]);
    ov[j] = (short)f2bf(v);
  }
  int k = n * 256 + q * 8;
  int kt = k >> 6, kc = (k >> 3) & 7;
  *(bf16x8*)(Ad + (size_t)p * 2304 + kt * 64 + (((kc ^ (p & 7)) << 3))) = ov;
}

// ---------------- MFMA GEMM body --------------------------------------------
// C^T[n][m] frags via swapped operands; BM=128, BK=64, 256 threads (4 waves).
// MODE 0: A = materialized Ad (deform, out ch 0..255, ReLU)
// MODE 1: A = virtual 5-tap from xTb (cdc, out ch 256..511, ReLU)
// MODE 2: A = virtual 9-tap from xTb (offmod, N=32/27, +bias, no ReLU)
template <int KTOT, int MODE>
__device__ __forceinline__ void gemm_body(
    const u16* __restrict__ Asrc, const u16* __restrict__ Bt,
    const float* __restrict__ p_b, const float* __restrict__ m_b,
    float* __restrict__ outp, int mt, int nt, u16* As, u16* Bs) {
  const int BN = (MODE == 2) ? 32 : 64;
  const int WM = (MODE == 2) ? 32 : 64;
  const int MF = WM / 16;
  const int OCH0 = (MODE == 1) ? 256 : 0;

  int tid = threadIdx.x;
  int wid = tid >> 6, lane = tid & 63;
  int wr = (MODE == 2) ? wid : (wid >> 1);
  int wc = (MODE == 2) ? 0 : (wid & 1);
  int pbase = mt * 128;
  int obase = nt * BN;
  int l8 = lane >> 3, l7 = lane & 7;
  int lr = lane & 15, lg = lane >> 4;

  f32x4 acc[2][4];
#pragma unroll
  for (int i = 0; i < 2; i++)
#pragma unroll
    for (int j = 0; j < 4; j++) acc[i][j] = {0.f, 0.f, 0.f, 0.f};

  const int dh1[5] = {0, 1, 1, 1, 2}, dw1[5] = {1, 0, 1, 2, 1};

  for (int kb = 0; kb < KTOT; kb += 64) {
    int kt = kb >> 6;
    // ---- stage A tile [128][64] ----
    if (MODE == 0) {
#pragma unroll
      for (int i = 0; i < 4; i++) {
        int r0 = wid * 32 + i * 8;
        const u16* g = Asrc + (size_t)(pbase + r0 + l8) * KTOT + kt * 64 + (l7 << 3);
        GLOAD16(g, &As[r0 * 64]);
      }
    } else {
      int t = kt >> 2, c0 = (kt & 3) << 6;
      int dh, dw;
      if (MODE == 1) { dh = dh1[t]; dw = dw1[t]; }
      else           { dh = t / 3;  dw = t % 3;  }
#pragma unroll
      for (int i = 0; i < 4; i++) {
        int r0 = wid * 32 + i * 8;
        int r = r0 + l8;
        int p = pbase + r;
        int b = p >> 12, hw = p & 4095, h = hw >> 6, w = hw & 63;
        int chunk = l7 ^ (r & 7);
        const u16* g = Asrc + (size_t)b * XT_BSTRIDE +
                       ((h + dh) * 66 + (w + dw)) * 256 + c0 + (chunk << 3);
        GLOAD16(g, &As[r0 * 64]);
      }
    }
    // ---- stage B tile [BN][64] ----
#pragma unroll
    for (int i = 0; i < BN / 32; i++) {
      int o0 = wid * (BN / 4) + i * 8;
      const u16* g = Bt + (size_t)(obase + o0 + l8) * KTOT + kt * 64 + (l7 << 3);
      GLOAD16(g, &Bs[o0 * 64]);
    }
    __syncthreads();

    bf16x8 av[4][2], bv[2][2];
#pragma unroll
    for (int mf = 0; mf < MF; mf++) {
      int r = wr * WM + mf * 16 + lr;
#pragma unroll
      for (int ks = 0; ks < 2; ks++) {
        int kc = ks * 4 + lg;
        av[mf][ks] = *(const bf16x8*)&As[r * 64 + ((kc ^ (r & 7)) << 3)];
      }
    }
#pragma unroll
    for (int nf = 0; nf < 2; nf++) {
      int o = wc * 32 + nf * 16 + lr;
#pragma unroll
      for (int ks = 0; ks < 2; ks++) {
        int kc = ks * 4 + lg;
        bv[nf][ks] = *(const bf16x8*)&Bs[o * 64 + ((kc ^ (o & 7)) << 3)];
      }
    }
#pragma unroll
    for (int nf = 0; nf < 2; nf++)
#pragma unroll
      for (int mf = 0; mf < MF; mf++)
#pragma unroll
        for (int ks = 0; ks < 2; ks++)
          acc[nf][mf] = __builtin_amdgcn_mfma_f32_16x16x32_bf16(
              bv[nf][ks], av[mf][ks], acc[nf][mf], 0, 0, 0);
    __syncthreads();
  }

  // ---- epilogue ----
  if (MODE != 2) {
#pragma unroll
    for (int nf = 0; nf < 2; nf++)
#pragma unroll
      for (int mf = 0; mf < MF; mf++) {
        int p = pbase + wr * WM + mf * 16 + lr;
        int hw = p & 4095, b = p >> 12;
        int og = OCH0 + obase + wc * 32 + nf * 16 + lg * 4;
        f32x4 v = acc[nf][mf];
#pragma unroll
        for (int e = 0; e < 4; e++)
          outp[(size_t)(b * 512 + og + e) * 4096 + hw] = fmaxf(v[e], 0.f);
      }
  } else {
#pragma unroll
    for (int nf = 0; nf < 2; nf++)
#pragma unroll
      for (int mf = 0; mf < 2; mf++) {
        int p = pbase + wr * 32 + mf * 16 + lr;
        int hw = p & 4095, b = p >> 12;
        int o0 = nf * 16 + lg * 4;
        f32x4 v = acc[nf][mf];
#pragma unroll
        for (int e = 0; e < 4; e++) {
          int o = o0 + e;
          if (o < 27) {
            float bias = (o < 18) ? p_b[o] : m_b[o - 18];
            outp[(size_t)(b * 27 + o) * 4096 + hw] = v[e] + bias;
          }
        }
      }
  }
}

__global__ __launch_bounds__(256) void gemm_offmod(const u16* __restrict__ xTb,
                                                   const u16* __restrict__ W1t,
                                                   const float* __restrict__ p_b,
                                                   const float* __restrict__ m_b,
                                                   float* __restrict__ offmod) {
  __shared__ u16 As[128 * 64];
  __shared__ u16 Bs[32 * 64];
  gemm_body<2304, 2>(xTb, W1t, p_b, m_b, offmod, blockIdx.x, 0, As, Bs);
}

__global__ __launch_bounds__(256) void gemm_main(const u16* __restrict__ Ad,
                                                 const u16* __restrict__ xTb,
                                                 const u16* __restrict__ Wdt,
                                                 const u16* __restrict__ Wct,
                                                 float* __restrict__ out) {
  __shared__ u16 As[128 * 64];
  __shared__ u16 Bs[64 * 64];
  int bx = blockIdx.x;
  if (bx < 256) {
    gemm_body<2304, 0>(Ad, Wdt, nullptr, nullptr, out, bx >> 2, bx & 3, As, Bs);
  } else {
    bx -= 256;
    gemm_body<1280, 1>(xTb, Wct, nullptr, nullptr, out, bx >> 2, bx & 3, As, Bs);
  }
}

// ---------------- launch ----------------------------------------------------
extern "C" void kernel_launch(void* const* d_in, const int* in_sizes, int n_in,
                              void* d_out, int out_size, void* d_ws, size_t ws_size,
                              hipStream_t stream) {
  (void)in_sizes; (void)n_in; (void)out_size; (void)ws_size;
  const float* x       = (const float*)d_in[0];
  const float* p_w     = (const float*)d_in[1];
  const float* p_b     = (const float*)d_in[2];
  const float* m_w     = (const float*)d_in[3];
  const float* m_b     = (const float*)d_in[4];
  const float* dconv_w = (const float*)d_in[5];
  const float* cdc_w   = (const float*)d_in[6];
  float* out = (float*)d_out;
  char* ws = (char*)d_ws;

  u16*   xTb    = (u16*)(ws);                  // 4,460,544 B
  float* offmod = (float*)(ws + 4460544);      //   884,736 B
  u16*   W1t    = (u16*)(ws + 5345280);        //   147,456 B
  u16*   Wdt    = (u16*)(ws + 5492736);        // 1,179,648 B
  u16*   Wct    = (u16*)(ws + 6672384);        //   655,360 B
  int4*  sidx   = (int4*)(ws + 7327744);       // 1,179,648 B
  float4* sg    = (float4*)(ws + 8507392);     // 1,179,648 B
  u16*   Ad     = (u16*)(ws + 9687040);        // 37,748,736 B  (end 47,435,776)

  hipMemsetAsync(xTb, 0, 4460544, stream);
  pad_transpose<<<512, 256, 0, stream>>>(x, xTb);
  prepack_w<<<3872, 256, 0, stream>>>(p_w, m_w, dconv_w, cdc_w, W1t, Wdt, Wct);
  gemm_offmod<<<64, 256, 0, stream>>>(xTb, W1t, p_b, m_b, offmod);
  sample_params<<<288, 256, 0, stream>>>(offmod, sidx, sg);
  gather_Ad<<<9216, 256, 0, stream>>>(xTb, sidx, sg, Ad);
  gemm_main<<<512, 256, 0, stream>>>(Ad, xTb, Wdt, Wct, out);
}

// Round 3
// 96.984 us; speedup vs baseline: 6.0910x; 1.0101x over previous
//
#include <hip/hip_runtime.h>
#include <hip/hip_bf16.h>
#include <math.h>

#define XT_BSTRIDE (66*66*256)
#define THETA_ 0.7f

typedef unsigned short u16;
typedef __attribute__((ext_vector_type(8))) short bf16x8;
typedef __attribute__((ext_vector_type(4))) float f32x4;

#define GLOAD16(gp, lp) __builtin_amdgcn_global_load_lds( \
    (const __attribute__((address_space(1))) unsigned int*)(gp), \
    (__attribute__((address_space(3))) unsigned int*)(lp), 16, 0, 0)

__device__ __forceinline__ float bf2f(u16 v) {
  union { unsigned u; float f; } x; x.u = ((unsigned)v) << 16; return x.f;
}
__device__ __forceinline__ u16 f2bf(float f) {
  __hip_bfloat16 h = __float2bfloat16(f);
  return *(u16*)&h;
}

// swizzled element index within a [rows][K] bf16 matrix: per 64-k tile, the
// 8-element chunks are XOR-permuted by (row&7) so that linear global_load_lds
// (8 rows x 8 chunks per wave-instr) lands them at XOR-swizzled LDS slots.
__device__ __forceinline__ size_t swz_idx(int row, int k, int KT) {
  int kt = k >> 6, kc = (k >> 3) & 7, kj = k & 7;
  return (size_t)row * KT + kt * 64 + ((kc ^ (row & 7)) << 3) + kj;
}

// ---------------- zero the 1-px padding border of xTb -----------------------
__global__ __launch_bounds__(256) void zero_border(u16* __restrict__ xTb) {
  int i = blockIdx.x * 256 + threadIdx.x;   // 2 * 260 * 256 = 133120
  if (i >= 133120) return;
  int c = i & 255;
  int j = i >> 8;                            // 0..519
  int b = (j >= 260) ? 1 : 0;
  int r = j - b * 260;                       // border pixel 0..259
  int hp, wp;
  if (r < 66)       { hp = 0;        wp = r; }
  else if (r < 132) { hp = 65;       wp = r - 66; }
  else if (r < 196) { hp = r - 131;  wp = 0; }
  else              { hp = r - 195;  wp = 65; }
  xTb[(size_t)b * XT_BSTRIDE + (hp * 66 + wp) * 256 + c] = 0;
}

// ---------------- pad + transpose + bf16: x -> xTb[b][hp][wp][c] ------------
__global__ __launch_bounds__(256) void pad_transpose(const float* __restrict__ x,
                                                     u16* __restrict__ xTb) {
  int blk = blockIdx.x;              // b(2) * h(64) * cg(4) = 512
  int cg = blk & 3;
  int h  = (blk >> 2) & 63;
  int b  = blk >> 8;
  __shared__ float tile[64][65];
  const float* xp = x + ((size_t)(b * 256 + cg * 64)) * 4096 + h * 64;
#pragma unroll
  for (int j = 0; j < 16; j++) {
    int idx = j * 256 + threadIdx.x;
    int ci = idx >> 6, w = idx & 63;
    tile[ci][w] = xp[(size_t)ci * 4096 + w];
  }
  __syncthreads();
  u16* xo = xTb + (size_t)b * XT_BSTRIDE + ((h + 1) * 66 + 1) * 256 + cg * 64;
#pragma unroll
  for (int j = 0; j < 16; j++) {
    int idx = j * 256 + threadIdx.x;
    int w = idx >> 6, ci = idx & 63;
    xo[(size_t)w * 256 + ci] = f2bf(tile[ci][w]);
  }
}

// ---------------- prepack weights (bf16, B^T, swizzled) ---------------------
// W1t[32][2304]  (o<18: p_w, o<27: m_w, else 0), k = kp*256+c
// Wdt[256][2304] k = n*256+c ;  Wct[256][1280] k = t*256+c (center tap folded)
__global__ void prepack_w(const float* __restrict__ p_w, const float* __restrict__ m_w,
                          const float* __restrict__ dconv_w, const float* __restrict__ cdc_w,
                          u16* __restrict__ W1t, u16* __restrict__ Wdt,
                          u16* __restrict__ Wct) {
  int i = blockIdx.x * 256 + threadIdx.x;
  if (i < 73728) {
    int o = i / 2304, k = i % 2304;
    int kp = k >> 8, c = k & 255;
    float v = 0.f;
    if (o < 18)      v = p_w[((size_t)o * 256 + c) * 9 + kp];
    else if (o < 27) v = m_w[((size_t)(o - 18) * 256 + c) * 9 + kp];
    W1t[swz_idx(o, k, 2304)] = f2bf(v);
    return;
  }
  int j = i - 73728;
  if (j < 589824) {
    int o = j / 2304, k = j % 2304;
    int n = k >> 8, c = k & 255;
    Wdt[swz_idx(o, k, 2304)] = f2bf(dconv_w[((size_t)o * 256 + c) * 9 + n]);
    return;
  }
  int j2 = j - 589824;
  if (j2 < 327680) {
    int o = j2 / 1280, k = j2 % 1280;
    int t = k >> 8, c = k & 255;
    const float* cw = cdc_w + ((size_t)o * 256 + c) * 5;
    float v = cw[t];
    if (t == 2) v -= THETA_ * (cw[0] + cw[1] + cw[2] + cw[3] + cw[4]);
    Wct[swz_idx(o, k, 1280)] = f2bf(v);
  }
}

// ---------------- sampling params: 4 corner indices + 4 (g*m) weights -------
__global__ void sample_params(const float* __restrict__ offmod,
                              int4* __restrict__ sidx, float4* __restrict__ sg) {
  int i = blockIdx.x * 256 + threadIdx.x;
  if (i >= 73728) return;
  int n = i % 9;
  int p = i / 9;
  int b = p >> 12;
  int hw = p & 4095;
  int h = hw >> 6, w = hw & 63;
  const float* om = offmod + (size_t)b * 27 * 4096;
  float offx = om[(size_t)n * 4096 + hw];
  float offy = om[(size_t)(9 + n) * 4096 + hw];
  float mraw = om[(size_t)(18 + n) * 4096 + hw];
  float px = offx + (float)(h + n / 3);
  float py = offy + (float)(w + n % 3);
  float fx = floorf(px), fy = floorf(py);
  float qx0 = fminf(fmaxf(fx, 0.f), 65.f);
  float qy0 = fminf(fmaxf(fy, 0.f), 65.f);
  float qx1 = fminf(fmaxf(fx + 1.f, 0.f), 65.f);
  float qy1 = fminf(fmaxf(fy + 1.f, 0.f), 65.f);
  float pxc = fminf(fmaxf(px, 0.f), 65.f);
  float pyc = fminf(fmaxf(py, 0.f), 65.f);
  float gx0 = 1.f + (qx0 - pxc);
  float gx1 = 1.f - (qx1 - pxc);
  float gy0 = 1.f + (qy0 - pyc);
  float gy1 = 1.f - (qy1 - pyc);
  float m = 1.f / (1.f + expf(-mraw));
  sidx[i] = make_int4((int)qx0 * 66 + (int)qy0, (int)qx1 * 66 + (int)qy1,
                      (int)qx0 * 66 + (int)qy1, (int)qx1 * 66 + (int)qy0);
  sg[i] = make_float4(gx0 * gy0 * m, gx1 * gy1 * m, gx0 * gy1 * m, gx1 * gy0 * m);
}

// ---------------- build A_d (bilinear gather), bf16, pre-swizzled -----------
__global__ __launch_bounds__(256) void gather_Ad(const u16* __restrict__ xTb,
                                                 const int4* __restrict__ sidx,
                                                 const float4* __restrict__ sg,
                                                 u16* __restrict__ Ad) {
  int gid = blockIdx.x * 256 + threadIdx.x;   // 2359296 total
  int q = gid & 31;                            // channel chunk (8 ch)
  int s = gid >> 5;                            // p*9+n
  int p = s / 9, n = s - p * 9;
  int b = p >> 12;
  int4 qi = sidx[s];
  float4 g = sg[s];
  const u16* xb = xTb + (size_t)b * XT_BSTRIDE + q * 8;
  bf16x8 a0 = *(const bf16x8*)(xb + (size_t)qi.x * 256);
  bf16x8 a1 = *(const bf16x8*)(xb + (size_t)qi.y * 256);
  bf16x8 a2 = *(const bf16x8*)(xb + (size_t)qi.z * 256);
  bf16x8 a3 = *(const bf16x8*)(xb + (size_t)qi.w * 256);
  bf16x8 ov;
#pragma unroll
  for (int j = 0; j < 8; j++) {
    float v = g.x * bf2f((u16)a0[j]) + g.y * bf2f((u16)a1[j]) +
              g.z * bf2f((u16)a2[j]) + g.w * bf2f((u16)a3[j]);
    ov[j] = (short)f2bf(v);
  }
  int k = n * 256 + q * 8;
  int kt = k >> 6, kc = (k >> 3) & 7;
  *(bf16x8*)(Ad + (size_t)p * 2304 + kt * 64 + (((kc ^ (p & 7)) << 3))) = ov;
}

// ---------------- MFMA GEMM body --------------------------------------------
// C^T[n][m] frags via swapped operands; BM=128, BK=64, 256 threads (4 waves).
// MODE 0: A = materialized Ad (deform, out ch 0..255, ReLU)
// MODE 1: A = virtual 5-tap from xTb (cdc, out ch 256..511, ReLU)
// MODE 2: A = virtual 9-tap from xTb (offmod, N=32/27, +bias, no ReLU)
template <int KTOT, int MODE>
__device__ __forceinline__ void gemm_body(
    const u16* __restrict__ Asrc, const u16* __restrict__ Bt,
    const float* __restrict__ p_b, const float* __restrict__ m_b,
    float* __restrict__ outp, int mt, int nt, u16* As, u16* Bs) {
  const int BN = (MODE == 2) ? 32 : 64;
  const int WM = (MODE == 2) ? 32 : 64;
  const int MF = WM / 16;
  const int OCH0 = (MODE == 1) ? 256 : 0;

  int tid = threadIdx.x;
  int wid = tid >> 6, lane = tid & 63;
  int wr = (MODE == 2) ? wid : (wid >> 1);
  int wc = (MODE == 2) ? 0 : (wid & 1);
  int pbase = mt * 128;
  int obase = nt * BN;
  int l8 = lane >> 3, l7 = lane & 7;
  int lr = lane & 15, lg = lane >> 4;

  f32x4 acc[2][4];
#pragma unroll
  for (int i = 0; i < 2; i++)
#pragma unroll
    for (int j = 0; j < 4; j++) acc[i][j] = {0.f, 0.f, 0.f, 0.f};

  const int dh1[5] = {0, 1, 1, 1, 2}, dw1[5] = {1, 0, 1, 2, 1};

  for (int kb = 0; kb < KTOT; kb += 64) {
    int kt = kb >> 6;
    // ---- stage A tile [128][64] ----
    if (MODE == 0) {
#pragma unroll
      for (int i = 0; i < 4; i++) {
        int r0 = wid * 32 + i * 8;
        const u16* g = Asrc + (size_t)(pbase + r0 + l8) * KTOT + kt * 64 + (l7 << 3);
        GLOAD16(g, &As[r0 * 64]);
      }
    } else {
      int t = kt >> 2, c0 = (kt & 3) << 6;
      int dh, dw;
      if (MODE == 1) { dh = dh1[t]; dw = dw1[t]; }
      else           { dh = t / 3;  dw = t % 3;  }
#pragma unroll
      for (int i = 0; i < 4; i++) {
        int r0 = wid * 32 + i * 8;
        int r = r0 + l8;
        int p = pbase + r;
        int b = p >> 12, hw = p & 4095, h = hw >> 6, w = hw & 63;
        int chunk = l7 ^ (r & 7);
        const u16* g = Asrc + (size_t)b * XT_BSTRIDE +
                       ((h + dh) * 66 + (w + dw)) * 256 + c0 + (chunk << 3);
        GLOAD16(g, &As[r0 * 64]);
      }
    }
    // ---- stage B tile [BN][64] ----
#pragma unroll
    for (int i = 0; i < BN / 32; i++) {
      int o0 = wid * (BN / 4) + i * 8;
      const u16* g = Bt + (size_t)(obase + o0 + l8) * KTOT + kt * 64 + (l7 << 3);
      GLOAD16(g, &Bs[o0 * 64]);
    }
    __syncthreads();

    bf16x8 av[4][2], bv[2][2];
#pragma unroll
    for (int mf = 0; mf < MF; mf++) {
      int r = wr * WM + mf * 16 + lr;
#pragma unroll
      for (int ks = 0; ks < 2; ks++) {
        int kc = ks * 4 + lg;
        av[mf][ks] = *(const bf16x8*)&As[r * 64 + ((kc ^ (r & 7)) << 3)];
      }
    }
#pragma unroll
    for (int nf = 0; nf < 2; nf++) {
      int o = wc * 32 + nf * 16 + lr;
#pragma unroll
      for (int ks = 0; ks < 2; ks++) {
        int kc = ks * 4 + lg;
        bv[nf][ks] = *(const bf16x8*)&Bs[o * 64 + ((kc ^ (o & 7)) << 3)];
      }
    }
#pragma unroll
    for (int nf = 0; nf < 2; nf++)
#pragma unroll
      for (int mf = 0; mf < MF; mf++)
#pragma unroll
        for (int ks = 0; ks < 2; ks++)
          acc[nf][mf] = __builtin_amdgcn_mfma_f32_16x16x32_bf16(
              bv[nf][ks], av[mf][ks], acc[nf][mf], 0, 0, 0);
    __syncthreads();
  }

  // ---- epilogue ----
  if (MODE != 2) {
#pragma unroll
    for (int nf = 0; nf < 2; nf++)
#pragma unroll
      for (int mf = 0; mf < MF; mf++) {
        int p = pbase + wr * WM + mf * 16 + lr;
        int hw = p & 4095, b = p >> 12;
        int og = OCH0 + obase + wc * 32 + nf * 16 + lg * 4;
        f32x4 v = acc[nf][mf];
#pragma unroll
        for (int e = 0; e < 4; e++)
          outp[(size_t)(b * 512 + og + e) * 4096 + hw] = fmaxf(v[e], 0.f);
      }
  } else {
#pragma unroll
    for (int nf = 0; nf < 2; nf++)
#pragma unroll
      for (int mf = 0; mf < 2; mf++) {
        int p = pbase + wr * 32 + mf * 16 + lr;
        int hw = p & 4095, b = p >> 12;
        int o0 = nf * 16 + lg * 4;
        f32x4 v = acc[nf][mf];
#pragma unroll
        for (int e = 0; e < 4; e++) {
          int o = o0 + e;
          if (o < 27) {
            float bias = (o < 18) ? p_b[o] : m_b[o - 18];
            outp[(size_t)(b * 27 + o) * 4096 + hw] = v[e] + bias;
          }
        }
      }
  }
}

__global__ __launch_bounds__(256) void gemm_offmod(const u16* __restrict__ xTb,
                                                   const u16* __restrict__ W1t,
                                                   const float* __restrict__ p_b,
                                                   const float* __restrict__ m_b,
                                                   float* __restrict__ offmod) {
  __shared__ u16 As[128 * 64];
  __shared__ u16 Bs[32 * 64];
  gemm_body<2304, 2>(xTb, W1t, p_b, m_b, offmod, blockIdx.x, 0, As, Bs);
}

__global__ __launch_bounds__(256) void gemm_main(const u16* __restrict__ Ad,
                                                 const u16* __restrict__ xTb,
                                                 const u16* __restrict__ Wdt,
                                                 const u16* __restrict__ Wct,
                                                 float* __restrict__ out) {
  __shared__ u16 As[128 * 64];
  __shared__ u16 Bs[64 * 64];
  int bx = blockIdx.x;
  if (bx < 256) {
    gemm_body<2304, 0>(Ad, Wdt, nullptr, nullptr, out, bx >> 2, bx & 3, As, Bs);
  } else {
    bx -= 256;
    gemm_body<1280, 1>(xTb, Wct, nullptr, nullptr, out, bx >> 2, bx & 3, As, Bs);
  }
}

// ---------------- launch ----------------------------------------------------
extern "C" void kernel_launch(void* const* d_in, const int* in_sizes, int n_in,
                              void* d_out, int out_size, void* d_ws, size_t ws_size,
                              hipStream_t stream) {
  (void)in_sizes; (void)n_in; (void)out_size; (void)ws_size;
  const float* x       = (const float*)d_in[0];
  const float* p_w     = (const float*)d_in[1];
  const float* p_b     = (const float*)d_in[2];
  const float* m_w     = (const float*)d_in[3];
  const float* m_b     = (const float*)d_in[4];
  const float* dconv_w = (const float*)d_in[5];
  const float* cdc_w   = (const float*)d_in[6];
  float* out = (float*)d_out;
  char* ws = (char*)d_ws;

  u16*   xTb    = (u16*)(ws);                  // 4,460,544 B
  float* offmod = (float*)(ws + 4460544);      //   884,736 B
  u16*   W1t    = (u16*)(ws + 5345280);        //   147,456 B
  u16*   Wdt    = (u16*)(ws + 5492736);        // 1,179,648 B
  u16*   Wct    = (u16*)(ws + 6672384);        //   655,360 B
  int4*  sidx   = (int4*)(ws + 7327744);       // 1,179,648 B
  float4* sg    = (float4*)(ws + 8507392);     // 1,179,648 B
  u16*   Ad     = (u16*)(ws + 9687040);        // 37,748,736 B  (end 47,435,776)

  zero_border<<<520, 256, 0, stream>>>(xTb);
  pad_transpose<<<512, 256, 0, stream>>>(x, xTb);
  prepack_w<<<3872, 256, 0, stream>>>(p_w, m_w, dconv_w, cdc_w, W1t, Wdt, Wct);
  gemm_offmod<<<64, 256, 0, stream>>>(xTb, W1t, p_b, m_b, offmod);
  sample_params<<<288, 256, 0, stream>>>(offmod, sidx, sg);
  gather_Ad<<<9216, 256, 0, stream>>>(xTb, sidx, sg, Ad);
  gemm_main<<<512, 256, 0, stream>>>(Ad, xTb, Wdt, Wct, out);
}

// Round 5
// 73.343 us; speedup vs baseline: 8.0543x; 1.3223x over previous
//
#include <hip/hip_runtime.h>
#include <hip/hip_bf16.h>
#include <math.h>

#define XT_BSTRIDE (66*66*256)
#define THETA_ 0.7f

typedef unsigned short u16;
typedef __attribute__((ext_vector_type(8))) short bf16x8;
typedef __attribute__((ext_vector_type(4))) float f32x4;

#define GLOAD16(gp, lp) __builtin_amdgcn_global_load_lds( \
    (const __attribute__((address_space(1))) unsigned int*)(gp), \
    (__attribute__((address_space(3))) unsigned int*)(lp), 16, 0, 0)

__device__ __forceinline__ float bf2f(u16 v) {
  union { unsigned u; float f; } x; x.u = ((unsigned)v) << 16; return x.f;
}
__device__ __forceinline__ u16 f2bf(float f) {
  __hip_bfloat16 h = __float2bfloat16(f);
  return *(u16*)&h;
}

// swizzled element index within a [rows][K] bf16 matrix: per 64-k tile, the
// 8-element chunks are XOR-permuted by (row&7) so that linear global_load_lds
// lands them at XOR-swizzled LDS slots (conflict-free ds_read_b128 later).
__device__ __forceinline__ size_t swz_idx(int row, int k, int KT) {
  int kt = k >> 6, kc = (k >> 3) & 7, kj = k & 7;
  return (size_t)row * KT + kt * 64 + ((kc ^ (row & 7)) << 3) + kj;
}

// ---------------- prep: zero border + pad/transpose + weight prepack --------
__global__ __launch_bounds__(256) void prep(
    const float* __restrict__ x, const float* __restrict__ p_w,
    const float* __restrict__ m_w, const float* __restrict__ dconv_w,
    const float* __restrict__ cdc_w, u16* __restrict__ xTb,
    u16* __restrict__ W1t, u16* __restrict__ Wdt, u16* __restrict__ Wct) {
  int blk = blockIdx.x;
  if (blk < 512) {
    // pad_transpose: b(2) * h(64) * cg(4)
    int cg = blk & 3;
    int h  = (blk >> 2) & 63;
    int b  = blk >> 8;
    __shared__ float tile[64][65];
    const float* xp = x + ((size_t)(b * 256 + cg * 64)) * 4096 + h * 64;
#pragma unroll
    for (int j = 0; j < 16; j++) {
      int idx = j * 256 + threadIdx.x;
      int ci = idx >> 6, w = idx & 63;
      tile[ci][w] = xp[(size_t)ci * 4096 + w];
    }
    __syncthreads();
    u16* xo = xTb + (size_t)b * XT_BSTRIDE + ((h + 1) * 66 + 1) * 256 + cg * 64;
#pragma unroll
    for (int j = 0; j < 16; j++) {
      int idx = j * 256 + threadIdx.x;
      int w = idx >> 6, ci = idx & 63;
      xo[(size_t)w * 256 + ci] = f2bf(tile[ci][w]);
    }
    return;
  }
  if (blk < 1032) {
    // zero the 1-px padding border: 2 * 260 * 256 = 133120
    int i = (blk - 512) * 256 + threadIdx.x;
    if (i >= 133120) return;
    int c = i & 255;
    int j = i >> 8;
    int b = (j >= 260) ? 1 : 0;
    int r = j - b * 260;
    int hp, wp;
    if (r < 66)       { hp = 0;        wp = r; }
    else if (r < 132) { hp = 65;       wp = r - 66; }
    else if (r < 196) { hp = r - 131;  wp = 0; }
    else              { hp = r - 195;  wp = 65; }
    xTb[(size_t)b * XT_BSTRIDE + (hp * 66 + wp) * 256 + c] = 0;
    return;
  }
  // prepack weights (bf16, B^T, swizzled); 991232 items
  int i = (blk - 1032) * 256 + threadIdx.x;
  if (i < 73728) {
    int o = i / 2304, k = i % 2304;
    int kp = k >> 8, c = k & 255;
    float v = 0.f;
    if (o < 18)      v = p_w[((size_t)o * 256 + c) * 9 + kp];
    else if (o < 27) v = m_w[((size_t)(o - 18) * 256 + c) * 9 + kp];
    W1t[swz_idx(o, k, 2304)] = f2bf(v);
    return;
  }
  int j = i - 73728;
  if (j < 589824) {
    int o = j / 2304, k = j % 2304;
    int n = k >> 8, c = k & 255;
    Wdt[swz_idx(o, k, 2304)] = f2bf(dconv_w[((size_t)o * 256 + c) * 9 + n]);
    return;
  }
  int j2 = j - 589824;
  if (j2 < 327680) {
    int o = j2 / 1280, k = j2 % 1280;
    int t = k >> 8, c = k & 255;
    const float* cw = cdc_w + ((size_t)o * 256 + c) * 5;
    float v = cw[t];
    if (t == 2) v -= THETA_ * (cw[0] + cw[1] + cw[2] + cw[3] + cw[4]);
    Wct[swz_idx(o, k, 1280)] = f2bf(v);
  }
}

// ---------------- sampling params (sums split-K partials, adds bias) --------
__global__ __launch_bounds__(256) void sample_params(
    const float* __restrict__ omp, const float* __restrict__ p_b,
    const float* __restrict__ m_b, int4* __restrict__ sidx,
    float4* __restrict__ sg) {
  int i = blockIdx.x * 256 + threadIdx.x;
  if (i >= 73728) return;
  int n = i % 9;
  int p = i / 9;
  int b = p >> 12;
  int hw = p & 4095;
  int h = hw >> 6, w = hw & 63;
  float offx = p_b[n], offy = p_b[9 + n], mraw = m_b[n];
#pragma unroll
  for (int ks = 0; ks < 4; ks++) {
    const float* base = omp + ks * 221184 + b * 110592;
    offx += base[(size_t)n * 4096 + hw];
    offy += base[(size_t)(9 + n) * 4096 + hw];
    mraw += base[(size_t)(18 + n) * 4096 + hw];
  }
  float px = offx + (float)(h + n / 3);
  float py = offy + (float)(w + n % 3);
  float fx = floorf(px), fy = floorf(py);
  float qx0 = fminf(fmaxf(fx, 0.f), 65.f);
  float qy0 = fminf(fmaxf(fy, 0.f), 65.f);
  float qx1 = fminf(fmaxf(fx + 1.f, 0.f), 65.f);
  float qy1 = fminf(fmaxf(fy + 1.f, 0.f), 65.f);
  float pxc = fminf(fmaxf(px, 0.f), 65.f);
  float pyc = fminf(fmaxf(py, 0.f), 65.f);
  float gx0 = 1.f + (qx0 - pxc);
  float gx1 = 1.f - (qx1 - pxc);
  float gy0 = 1.f + (qy0 - pyc);
  float gy1 = 1.f - (qy1 - pyc);
  float m = 1.f / (1.f + expf(-mraw));
  sidx[i] = make_int4((int)qx0 * 66 + (int)qy0, (int)qx1 * 66 + (int)qy1,
                      (int)qx0 * 66 + (int)qy1, (int)qx1 * 66 + (int)qy0);
  sg[i] = make_float4(gx0 * gy0 * m, gx1 * gy1 * m, gx0 * gy1 * m, gx1 * gy0 * m);
}

// ---------------- build A_d (bilinear gather), bf16, pre-swizzled -----------
__global__ __launch_bounds__(256) void gather_Ad(const u16* __restrict__ xTb,
                                                 const int4* __restrict__ sidx,
                                                 const float4* __restrict__ sg,
                                                 u16* __restrict__ Ad) {
  int gid = blockIdx.x * 256 + threadIdx.x;   // 2359296 total
  int q = gid & 31;                            // channel chunk (8 ch)
  int s = gid >> 5;                            // p*9+n
  int p = s / 9, n = s - p * 9;
  int b = p >> 12;
  int4 qi = sidx[s];
  float4 g = sg[s];
  const u16* xb = xTb + (size_t)b * XT_BSTRIDE + q * 8;
  bf16x8 a0 = *(const bf16x8*)(xb + (size_t)qi.x * 256);
  bf16x8 a1 = *(const bf16x8*)(xb + (size_t)qi.y * 256);
  bf16x8 a2 = *(const bf16x8*)(xb + (size_t)qi.z * 256);
  bf16x8 a3 = *(const bf16x8*)(xb + (size_t)qi.w * 256);
  bf16x8 ov;
#pragma unroll
  for (int j = 0; j < 8; j++) {
    float v = g.x * bf2f((u16)a0[j]) + g.y * bf2f((u16)a1[j]) +
              g.z * bf2f((u16)a2[j]) + g.w * bf2f((u16)a3[j]);
    ov[j] = (short)f2bf(v);
  }
  int k = n * 256 + q * 8;
  int kt = k >> 6, kc = (k >> 3) & 7;
  *(bf16x8*)(Ad + (size_t)p * 2304 + kt * 64 + (((kc ^ (p & 7)) << 3))) = ov;
}

// ---------------- MFMA GEMM body (2-phase double-buffered) ------------------
// C^T[n][m] frags via swapped operands; BM=128, BK=64, 256 threads (4 waves).
// MODE 0: A = materialized Ad (deform, out ch 0..255, ReLU)
// MODE 1: A = virtual 5-tap from xTb (cdc, out ch 256..511, ReLU)
// MODE 2: A = virtual 9-tap from xTb (offmod partial, N=32/27, no bias)
template <int KTOT, int MODE>
__device__ __forceinline__ void gemm_body(
    const u16* __restrict__ Asrc, const u16* __restrict__ Bt,
    float* __restrict__ outp, int mt, int nt, int kt0, int nkt,
    u16* As, u16* Bs) {
  const int BN = (MODE == 2) ? 32 : 64;
  const int WM = (MODE == 2) ? 32 : 64;
  const int MF = WM / 16;
  const int OCH0 = (MODE == 1) ? 256 : 0;

  int tid = threadIdx.x;
  int wid = tid >> 6, lane = tid & 63;
  int wr = (MODE == 2) ? wid : (wid >> 1);
  int wc = (MODE == 2) ? 0 : (wid & 1);
  int pbase = mt * 128;
  int obase = nt * BN;
  int l8 = lane >> 3, l7 = lane & 7;
  int lr = lane & 15, lg = lane >> 4;

  f32x4 acc[2][4];
#pragma unroll
  for (int i = 0; i < 2; i++)
#pragma unroll
    for (int j = 0; j < 4; j++) acc[i][j] = {0.f, 0.f, 0.f, 0.f};

  const int dh1[5] = {0, 1, 1, 1, 2}, dw1[5] = {1, 0, 1, 2, 1};

  auto stage = [&](int kt, u16* Ad_, u16* Bd_) {
    if (MODE == 0) {
#pragma unroll
      for (int i = 0; i < 4; i++) {
        int r0 = wid * 32 + i * 8;
        const u16* g = Asrc + (size_t)(pbase + r0 + l8) * KTOT + kt * 64 + (l7 << 3);
        GLOAD16(g, &Ad_[r0 * 64]);
      }
    } else {
      int t = kt >> 2, c0 = (kt & 3) << 6;
      int dh, dw;
      if (MODE == 1) { dh = dh1[t]; dw = dw1[t]; }
      else           { dh = t / 3;  dw = t % 3;  }
#pragma unroll
      for (int i = 0; i < 4; i++) {
        int r0 = wid * 32 + i * 8;
        int r = r0 + l8;
        int p = pbase + r;
        int b = p >> 12, hw = p & 4095, h = hw >> 6, w = hw & 63;
        int chunk = l7 ^ (r & 7);
        const u16* g = Asrc + (size_t)b * XT_BSTRIDE +
                       ((h + dh) * 66 + (w + dw)) * 256 + c0 + (chunk << 3);
        GLOAD16(g, &Ad_[r0 * 64]);
      }
    }
#pragma unroll
    for (int i = 0; i < BN / 32; i++) {
      int o0 = wid * (BN / 4) + i * 8;
      const u16* g = Bt + (size_t)(obase + o0 + l8) * KTOT + kt * 64 + (l7 << 3);
      GLOAD16(g, &Bd_[o0 * 64]);
    }
  };

  // prologue: stage first tile into half 0
  stage(kt0, As, Bs);
  __syncthreads();

  for (int it = 0; it < nkt; it++) {
    int cur = it & 1;
    u16* Ac = As + cur * (128 * 64);
    u16* Bc = Bs + cur * (BN * 64);
    if (it + 1 < nkt)
      stage(kt0 + it + 1, As + (cur ^ 1) * (128 * 64), Bs + (cur ^ 1) * (BN * 64));

    bf16x8 av[4][2], bv[2][2];
#pragma unroll
    for (int mf = 0; mf < MF; mf++) {
      int r = wr * WM + mf * 16 + lr;
#pragma unroll
      for (int ks = 0; ks < 2; ks++) {
        int kc = ks * 4 + lg;
        av[mf][ks] = *(const bf16x8*)&Ac[r * 64 + ((kc ^ (r & 7)) << 3)];
      }
    }
#pragma unroll
    for (int nf = 0; nf < 2; nf++) {
      int o = wc * 32 + nf * 16 + lr;
#pragma unroll
      for (int ks = 0; ks < 2; ks++) {
        int kc = ks * 4 + lg;
        bv[nf][ks] = *(const bf16x8*)&Bc[o * 64 + ((kc ^ (o & 7)) << 3)];
      }
    }
#pragma unroll
    for (int nf = 0; nf < 2; nf++)
#pragma unroll
      for (int mf = 0; mf < MF; mf++)
#pragma unroll
        for (int ks = 0; ks < 2; ks++)
          acc[nf][mf] = __builtin_amdgcn_mfma_f32_16x16x32_bf16(
              bv[nf][ks], av[mf][ks], acc[nf][mf], 0, 0, 0);
    __syncthreads();
  }

  // ---- epilogue ----
  if (MODE != 2) {
#pragma unroll
    for (int nf = 0; nf < 2; nf++)
#pragma unroll
      for (int mf = 0; mf < MF; mf++) {
        int p = pbase + wr * WM + mf * 16 + lr;
        int hw = p & 4095, b = p >> 12;
        int og = OCH0 + obase + wc * 32 + nf * 16 + lg * 4;
        f32x4 v = acc[nf][mf];
#pragma unroll
        for (int e = 0; e < 4; e++)
          outp[(size_t)(b * 512 + og + e) * 4096 + hw] = fmaxf(v[e], 0.f);
      }
  } else {
#pragma unroll
    for (int nf = 0; nf < 2; nf++)
#pragma unroll
      for (int mf = 0; mf < 2; mf++) {
        int p = pbase + wr * 32 + mf * 16 + lr;
        int hw = p & 4095, b = p >> 12;
        int o0 = nf * 16 + lg * 4;
        f32x4 v = acc[nf][mf];
#pragma unroll
        for (int e = 0; e < 4; e++) {
          int o = o0 + e;
          if (o < 27)
            outp[(size_t)(b * 27 + o) * 4096 + hw] = v[e];
        }
      }
  }
}

// offmod partial GEMM: 64 mt-tiles x 4 K-slices (9 tiles of 64 each)
__global__ __launch_bounds__(256) void gemm_offmod(const u16* __restrict__ xTb,
                                                   const u16* __restrict__ W1t,
                                                   float* __restrict__ omp) {
  __shared__ u16 As[2 * 128 * 64];
  __shared__ u16 Bs[2 * 32 * 64];
  int mt = blockIdx.x & 63;
  int ks = blockIdx.x >> 6;
  gemm_body<2304, 2>(xTb, W1t, omp + ks * 221184, mt, 0, ks * 9, 9, As, Bs);
}

__global__ __launch_bounds__(256) void gemm_main(const u16* __restrict__ Ad,
                                                 const u16* __restrict__ xTb,
                                                 const u16* __restrict__ Wdt,
                                                 const u16* __restrict__ Wct,
                                                 float* __restrict__ out) {
  __shared__ u16 As[2 * 128 * 64];
  __shared__ u16 Bs[2 * 64 * 64];
  int bx = blockIdx.x;
  if (bx < 256) {
    gemm_body<2304, 0>(Ad, Wdt, out, bx >> 2, bx & 3, 0, 36, As, Bs);
  } else {
    bx -= 256;
    gemm_body<1280, 1>(xTb, Wct, out, bx >> 2, bx & 3, 0, 20, As, Bs);
  }
}

// ---------------- launch ----------------------------------------------------
extern "C" void kernel_launch(void* const* d_in, const int* in_sizes, int n_in,
                              void* d_out, int out_size, void* d_ws, size_t ws_size,
                              hipStream_t stream) {
  (void)in_sizes; (void)n_in; (void)out_size; (void)ws_size;
  const float* x       = (const float*)d_in[0];
  const float* p_w     = (const float*)d_in[1];
  const float* p_b     = (const float*)d_in[2];
  const float* m_w     = (const float*)d_in[3];
  const float* m_b     = (const float*)d_in[4];
  const float* dconv_w = (const float*)d_in[5];
  const float* cdc_w   = (const float*)d_in[6];
  float* out = (float*)d_out;
  char* ws = (char*)d_ws;

  u16*   xTb  = (u16*)(ws);                   // 4,460,544 B
  float* omp  = (float*)(ws + 4460544);       // 3,538,944 B (4 K-slices)
  u16*   W1t  = (u16*)(ws + 7999488);         //   147,456 B
  u16*   Wdt  = (u16*)(ws + 8146944);         // 1,179,648 B
  u16*   Wct  = (u16*)(ws + 9326592);         //   655,360 B
  int4*  sidx = (int4*)(ws + 9981952);        // 1,179,648 B
  float4* sg  = (float4*)(ws + 11161600);     // 1,179,648 B
  u16*   Ad   = (u16*)(ws + 12341248);        // 37,748,736 B (end 50,089,984)

  prep<<<4904, 256, 0, stream>>>(x, p_w, m_w, dconv_w, cdc_w, xTb, W1t, Wdt, Wct);
  gemm_offmod<<<256, 256, 0, stream>>>(xTb, W1t, omp);
  sample_params<<<288, 256, 0, stream>>>(omp, p_b, m_b, sidx, sg);
  gather_Ad<<<9216, 256, 0, stream>>>(xTb, sidx, sg, Ad);
  gemm_main<<<512, 256, 0, stream>>>(Ad, xTb, Wdt, Wct, out);
}

// Round 6
// 68.819 us; speedup vs baseline: 8.5839x; 1.0657x over previous
//
#include <hip/hip_runtime.h>
#include <hip/hip_bf16.h>
#include <math.h>

#define XT_BSTRIDE (66*66*256)
#define THETA_ 0.7f

typedef unsigned short u16;
typedef __attribute__((ext_vector_type(8))) short bf16x8;
typedef __attribute__((ext_vector_type(4))) float f32x4;

#define GLOAD16(gp, lp) __builtin_amdgcn_global_load_lds( \
    (const __attribute__((address_space(1))) unsigned int*)(gp), \
    (__attribute__((address_space(3))) unsigned int*)(lp), 16, 0, 0)

__device__ __forceinline__ float bf2f(u16 v) {
  union { unsigned u; float f; } x; x.u = ((unsigned)v) << 16; return x.f;
}
__device__ __forceinline__ u16 f2bf(float f) {
  __hip_bfloat16 h = __float2bfloat16(f);
  return *(u16*)&h;
}

// swizzled element index within a [rows][K] bf16 matrix: per 64-k tile, the
// 8-element chunks are XOR-permuted by (row&7) so that linear global_load_lds
// lands them at XOR-swizzled LDS slots (conflict-free ds_read_b128 later).
__device__ __forceinline__ size_t swz_idx(int row, int k, int KT) {
  int kt = k >> 6, kc = (k >> 3) & 7, kj = k & 7;
  return (size_t)row * KT + kt * 64 + ((kc ^ (row & 7)) << 3) + kj;
}

// ---------------- prep: zero border + pad/transpose + weight prepack --------
__global__ __launch_bounds__(256) void prep(
    const float* __restrict__ x, const float* __restrict__ p_w,
    const float* __restrict__ m_w, const float* __restrict__ dconv_w,
    const float* __restrict__ cdc_w, u16* __restrict__ xTb,
    u16* __restrict__ W1t, u16* __restrict__ Wdt, u16* __restrict__ Wct) {
  int blk = blockIdx.x;
  if (blk < 512) {
    // pad_transpose: b(2) * h(64) * cg(4)
    int cg = blk & 3;
    int h  = (blk >> 2) & 63;
    int b  = blk >> 8;
    __shared__ float tile[64][65];
    const float* xp = x + ((size_t)(b * 256 + cg * 64)) * 4096 + h * 64;
#pragma unroll
    for (int j = 0; j < 16; j++) {
      int idx = j * 256 + threadIdx.x;
      int ci = idx >> 6, w = idx & 63;
      tile[ci][w] = xp[(size_t)ci * 4096 + w];
    }
    __syncthreads();
    u16* xo = xTb + (size_t)b * XT_BSTRIDE + ((h + 1) * 66 + 1) * 256 + cg * 64;
#pragma unroll
    for (int j = 0; j < 16; j++) {
      int idx = j * 256 + threadIdx.x;
      int w = idx >> 6, ci = idx & 63;
      xo[(size_t)w * 256 + ci] = f2bf(tile[ci][w]);
    }
    return;
  }
  if (blk < 1032) {
    // zero the 1-px padding border: 2 * 260 * 256 = 133120
    int i = (blk - 512) * 256 + threadIdx.x;
    if (i >= 133120) return;
    int c = i & 255;
    int j = i >> 8;
    int b = (j >= 260) ? 1 : 0;
    int r = j - b * 260;
    int hp, wp;
    if (r < 66)       { hp = 0;        wp = r; }
    else if (r < 132) { hp = 65;       wp = r - 66; }
    else if (r < 196) { hp = r - 131;  wp = 0; }
    else              { hp = r - 195;  wp = 65; }
    xTb[(size_t)b * XT_BSTRIDE + (hp * 66 + wp) * 256 + c] = 0;
    return;
  }
  // prepack weights (bf16, B^T, swizzled); 991232 items
  int i = (blk - 1032) * 256 + threadIdx.x;
  if (i < 73728) {
    int o = i / 2304, k = i % 2304;
    int kp = k >> 8, c = k & 255;
    float v = 0.f;
    if (o < 18)      v = p_w[((size_t)o * 256 + c) * 9 + kp];
    else if (o < 27) v = m_w[((size_t)(o - 18) * 256 + c) * 9 + kp];
    W1t[swz_idx(o, k, 2304)] = f2bf(v);
    return;
  }
  int j = i - 73728;
  if (j < 589824) {
    int o = j / 2304, k = j % 2304;
    int n = k >> 8, c = k & 255;
    Wdt[swz_idx(o, k, 2304)] = f2bf(dconv_w[((size_t)o * 256 + c) * 9 + n]);
    return;
  }
  int j2 = j - 589824;
  if (j2 < 327680) {
    int o = j2 / 1280, k = j2 % 1280;
    int t = k >> 8, c = k & 255;
    const float* cw = cdc_w + ((size_t)o * 256 + c) * 5;
    float v = cw[t];
    if (t == 2) v -= THETA_ * (cw[0] + cw[1] + cw[2] + cw[3] + cw[4]);
    Wct[swz_idx(o, k, 1280)] = f2bf(v);
  }
}

// ---------------- sampling params (sums split-K partials, adds bias) --------
__global__ __launch_bounds__(256) void sample_params(
    const float* __restrict__ omp, const float* __restrict__ p_b,
    const float* __restrict__ m_b, int4* __restrict__ sidx,
    float4* __restrict__ sg) {
  int i = blockIdx.x * 256 + threadIdx.x;
  if (i >= 73728) return;
  int n = i % 9;
  int p = i / 9;
  int b = p >> 12;
  int hw = p & 4095;
  int h = hw >> 6, w = hw & 63;
  float offx = p_b[n], offy = p_b[9 + n], mraw = m_b[n];
#pragma unroll
  for (int ks = 0; ks < 4; ks++) {
    const float* base = omp + ks * 221184 + b * 110592;
    offx += base[(size_t)n * 4096 + hw];
    offy += base[(size_t)(9 + n) * 4096 + hw];
    mraw += base[(size_t)(18 + n) * 4096 + hw];
  }
  float px = offx + (float)(h + n / 3);
  float py = offy + (float)(w + n % 3);
  float fx = floorf(px), fy = floorf(py);
  float qx0 = fminf(fmaxf(fx, 0.f), 65.f);
  float qy0 = fminf(fmaxf(fy, 0.f), 65.f);
  float qx1 = fminf(fmaxf(fx + 1.f, 0.f), 65.f);
  float qy1 = fminf(fmaxf(fy + 1.f, 0.f), 65.f);
  float pxc = fminf(fmaxf(px, 0.f), 65.f);
  float pyc = fminf(fmaxf(py, 0.f), 65.f);
  float gx0 = 1.f + (qx0 - pxc);
  float gx1 = 1.f - (qx1 - pxc);
  float gy0 = 1.f + (qy0 - pyc);
  float gy1 = 1.f - (qy1 - pyc);
  float m = 1.f / (1.f + expf(-mraw));
  sidx[i] = make_int4((int)qx0 * 66 + (int)qy0, (int)qx1 * 66 + (int)qy1,
                      (int)qx0 * 66 + (int)qy1, (int)qx1 * 66 + (int)qy0);
  sg[i] = make_float4(gx0 * gy0 * m, gx1 * gy1 * m, gx0 * gy1 * m, gx1 * gy0 * m);
}

// ---------------- build A_d (bilinear gather), bf16, pre-swizzled -----------
__global__ __launch_bounds__(256) void gather_Ad(const u16* __restrict__ xTb,
                                                 const int4* __restrict__ sidx,
                                                 const float4* __restrict__ sg,
                                                 u16* __restrict__ Ad) {
  int gid = blockIdx.x * 256 + threadIdx.x;   // 2359296 total
  int q = gid & 31;                            // channel chunk (8 ch)
  int s = gid >> 5;                            // p*9+n
  int p = s / 9, n = s - p * 9;
  int b = p >> 12;
  int4 qi = sidx[s];
  float4 g = sg[s];
  const u16* xb = xTb + (size_t)b * XT_BSTRIDE + q * 8;
  bf16x8 a0 = *(const bf16x8*)(xb + (size_t)qi.x * 256);
  bf16x8 a1 = *(const bf16x8*)(xb + (size_t)qi.y * 256);
  bf16x8 a2 = *(const bf16x8*)(xb + (size_t)qi.z * 256);
  bf16x8 a3 = *(const bf16x8*)(xb + (size_t)qi.w * 256);
  bf16x8 ov;
#pragma unroll
  for (int j = 0; j < 8; j++) {
    float v = g.x * bf2f((u16)a0[j]) + g.y * bf2f((u16)a1[j]) +
              g.z * bf2f((u16)a2[j]) + g.w * bf2f((u16)a3[j]);
    ov[j] = (short)f2bf(v);
  }
  int k = n * 256 + q * 8;
  int kt = k >> 6, kc = (k >> 3) & 7;
  *(bf16x8*)(Ad + (size_t)p * 2304 + kt * 64 + (((kc ^ (p & 7)) << 3))) = ov;
}

// ---------------- MFMA GEMM body (2-phase double-buffered) ------------------
// C^T[n][m] frags via swapped operands; BM=128, BK=64, 256 threads (4 waves).
// MODE 0: A = materialized Ad (deform, out ch 0..255, ReLU)
// MODE 1: A = virtual 5-tap from xTb (cdc, out ch 256..511, ReLU)
// MODE 2: A = virtual 9-tap from xTb (offmod partial, N=32/27, no bias)
template <int KTOT, int MODE>
__device__ __forceinline__ void gemm_body(
    const u16* __restrict__ Asrc, const u16* __restrict__ Bt,
    float* __restrict__ outp, int mt, int nt, int kt0, int nkt,
    u16* As, u16* Bs) {
  const int BN = (MODE == 2) ? 32 : 64;
  const int WM = (MODE == 2) ? 32 : 64;
  const int MF = WM / 16;
  const int OCH0 = (MODE == 1) ? 256 : 0;

  int tid = threadIdx.x;
  int wid = tid >> 6, lane = tid & 63;
  int wr = (MODE == 2) ? wid : (wid >> 1);
  int wc = (MODE == 2) ? 0 : (wid & 1);
  int pbase = mt * 128;
  int obase = nt * BN;
  int l8 = lane >> 3, l7 = lane & 7;
  int lr = lane & 15, lg = lane >> 4;

  f32x4 acc[2][4];
#pragma unroll
  for (int i = 0; i < 2; i++)
#pragma unroll
    for (int j = 0; j < 4; j++) acc[i][j] = {0.f, 0.f, 0.f, 0.f};

  const int dh1[5] = {0, 1, 1, 1, 2}, dw1[5] = {1, 0, 1, 2, 1};

  auto stage = [&](int kt, u16* Ad_, u16* Bd_) {
    if (MODE == 0) {
#pragma unroll
      for (int i = 0; i < 4; i++) {
        int r0 = wid * 32 + i * 8;
        const u16* g = Asrc + (size_t)(pbase + r0 + l8) * KTOT + kt * 64 + (l7 << 3);
        GLOAD16(g, &Ad_[r0 * 64]);
      }
    } else {
      int t = kt >> 2, c0 = (kt & 3) << 6;
      int dh, dw;
      if (MODE == 1) { dh = dh1[t]; dw = dw1[t]; }
      else           { dh = t / 3;  dw = t % 3;  }
#pragma unroll
      for (int i = 0; i < 4; i++) {
        int r0 = wid * 32 + i * 8;
        int r = r0 + l8;
        int p = pbase + r;
        int b = p >> 12, hw = p & 4095, h = hw >> 6, w = hw & 63;
        int chunk = l7 ^ (r & 7);
        const u16* g = Asrc + (size_t)b * XT_BSTRIDE +
                       ((h + dh) * 66 + (w + dw)) * 256 + c0 + (chunk << 3);
        GLOAD16(g, &Ad_[r0 * 64]);
      }
    }
#pragma unroll
    for (int i = 0; i < BN / 32; i++) {
      int o0 = wid * (BN / 4) + i * 8;
      const u16* g = Bt + (size_t)(obase + o0 + l8) * KTOT + kt * 64 + (l7 << 3);
      GLOAD16(g, &Bd_[o0 * 64]);
    }
  };

  // prologue: stage first tile into half 0
  stage(kt0, As, Bs);
  __syncthreads();

  for (int it = 0; it < nkt; it++) {
    int cur = it & 1;
    u16* Ac = As + cur * (128 * 64);
    u16* Bc = Bs + cur * (BN * 64);
    if (it + 1 < nkt)
      stage(kt0 + it + 1, As + (cur ^ 1) * (128 * 64), Bs + (cur ^ 1) * (BN * 64));

    bf16x8 av[4][2], bv[2][2];
#pragma unroll
    for (int mf = 0; mf < MF; mf++) {
      int r = wr * WM + mf * 16 + lr;
#pragma unroll
      for (int ks = 0; ks < 2; ks++) {
        int kc = ks * 4 + lg;
        av[mf][ks] = *(const bf16x8*)&Ac[r * 64 + ((kc ^ (r & 7)) << 3)];
      }
    }
#pragma unroll
    for (int nf = 0; nf < 2; nf++) {
      int o = wc * 32 + nf * 16 + lr;
#pragma unroll
      for (int ks = 0; ks < 2; ks++) {
        int kc = ks * 4 + lg;
        bv[nf][ks] = *(const bf16x8*)&Bc[o * 64 + ((kc ^ (o & 7)) << 3)];
      }
    }
#pragma unroll
    for (int nf = 0; nf < 2; nf++)
#pragma unroll
      for (int mf = 0; mf < MF; mf++)
#pragma unroll
        for (int ks = 0; ks < 2; ks++)
          acc[nf][mf] = __builtin_amdgcn_mfma_f32_16x16x32_bf16(
              bv[nf][ks], av[mf][ks], acc[nf][mf], 0, 0, 0);
    __syncthreads();
  }

  // ---- epilogue ----
  if (MODE != 2) {
#pragma unroll
    for (int nf = 0; nf < 2; nf++)
#pragma unroll
      for (int mf = 0; mf < MF; mf++) {
        int p = pbase + wr * WM + mf * 16 + lr;
        int hw = p & 4095, b = p >> 12;
        int og = OCH0 + obase + wc * 32 + nf * 16 + lg * 4;
        f32x4 v = acc[nf][mf];
#pragma unroll
        for (int e = 0; e < 4; e++)
          outp[(size_t)(b * 512 + og + e) * 4096 + hw] = fmaxf(v[e], 0.f);
      }
  } else {
#pragma unroll
    for (int nf = 0; nf < 2; nf++)
#pragma unroll
      for (int mf = 0; mf < 2; mf++) {
        int p = pbase + wr * 32 + mf * 16 + lr;
        int hw = p & 4095, b = p >> 12;
        int o0 = nf * 16 + lg * 4;
        f32x4 v = acc[nf][mf];
#pragma unroll
        for (int e = 0; e < 4; e++) {
          int o = o0 + e;
          if (o < 27)
            outp[(size_t)(b * 27 + o) * 4096 + hw] = v[e];
        }
      }
  }
}

// offmod partial GEMM: 64 mt-tiles x 4 K-slices (9 tiles of 64 each)
// XCD-aware: xcd = bid&7 gets mt in [xcd*8, xcd*8+8), all 4 K-slices -> xTb
// rows for those pixels are fetched into one L2.
__global__ __launch_bounds__(256) void gemm_offmod(const u16* __restrict__ xTb,
                                                   const u16* __restrict__ W1t,
                                                   float* __restrict__ omp) {
  __shared__ u16 As[2 * 128 * 64];
  __shared__ u16 Bs[2 * 32 * 64];
  int bid = blockIdx.x;
  int xcd = bid & 7;
  int i = bid >> 3;                 // 0..31
  int mt = xcd * 8 + (i & 7);
  int ks = i >> 3;                  // 0..3
  gemm_body<2304, 2>(xTb, W1t, omp + ks * 221184, mt, 0, ks * 9, 9, As, Bs);
}

// gemm_main XCD-aware mapping: each XCD handles 8 consecutive mt; the 4
// nt-blocks sharing an Ad slab land on the SAME XCD (one L2 fetch of the
// slab instead of 4); 32 deform + 32 cdc blocks per XCD balance the tail.
__global__ __launch_bounds__(256) void gemm_main(const u16* __restrict__ Ad,
                                                 const u16* __restrict__ xTb,
                                                 const u16* __restrict__ Wdt,
                                                 const u16* __restrict__ Wct,
                                                 float* __restrict__ out) {
  __shared__ u16 As[2 * 128 * 64];
  __shared__ u16 Bs[2 * 64 * 64];
  int bid = blockIdx.x;
  int xcd = bid & 7;
  int i = bid >> 3;                 // 0..63
  if (i < 32) {
    int mt = xcd * 8 + (i >> 2);
    int nt = i & 3;
    gemm_body<2304, 0>(Ad, Wdt, out, mt, nt, 0, 36, As, Bs);
  } else {
    i -= 32;
    int mt = xcd * 8 + (i >> 2);
    int nt = i & 3;
    gemm_body<1280, 1>(xTb, Wct, out, mt, nt, 0, 20, As, Bs);
  }
}

// ---------------- launch ----------------------------------------------------
extern "C" void kernel_launch(void* const* d_in, const int* in_sizes, int n_in,
                              void* d_out, int out_size, void* d_ws, size_t ws_size,
                              hipStream_t stream) {
  (void)in_sizes; (void)n_in; (void)out_size; (void)ws_size;
  const float* x       = (const float*)d_in[0];
  const float* p_w     = (const float*)d_in[1];
  const float* p_b     = (const float*)d_in[2];
  const float* m_w     = (const float*)d_in[3];
  const float* m_b     = (const float*)d_in[4];
  const float* dconv_w = (const float*)d_in[5];
  const float* cdc_w   = (const float*)d_in[6];
  float* out = (float*)d_out;
  char* ws = (char*)d_ws;

  u16*   xTb  = (u16*)(ws);                   // 4,460,544 B
  float* omp  = (float*)(ws + 4460544);       // 3,538,944 B (4 K-slices)
  u16*   W1t  = (u16*)(ws + 7999488);         //   147,456 B
  u16*   Wdt  = (u16*)(ws + 8146944);         // 1,179,648 B
  u16*   Wct  = (u16*)(ws + 9326592);         //   655,360 B
  int4*  sidx = (int4*)(ws + 9981952);        // 1,179,648 B
  float4* sg  = (float4*)(ws + 11161600);     // 1,179,648 B
  u16*   Ad   = (u16*)(ws + 12341248);        // 37,748,736 B (end 50,089,984)

  prep<<<4904, 256, 0, stream>>>(x, p_w, m_w, dconv_w, cdc_w, xTb, W1t, Wdt, Wct);
  gemm_offmod<<<256, 256, 0, stream>>>(xTb, W1t, omp);
  sample_params<<<288, 256, 0, stream>>>(omp, p_b, m_b, sidx, sg);
  gather_Ad<<<9216, 256, 0, stream>>>(xTb, sidx, sg, Ad);
  gemm_main<<<512, 256, 0, stream>>>(Ad, xTb, Wdt, Wct, out);
}